// Round 1
// baseline (107.967 us; speedup 1.0000x reference)
//
#include <hip/hip_runtime.h>
#include <math.h>

// tanh(delta^T M delta) for pairs of 20 amino-acid feature rows.
// idx in [0,20) => only 400 distinct outputs. Precompute table, then gather.

constexpr int NUM_AA = 20;
constexpr int FEAT   = 16;
constexpr int TABLE  = NUM_AA * NUM_AA; // 400

// ---------------- Kernel A: build the 400-entry lookup table ----------------
__global__ __launch_bounds__(512) void build_table(
    const float* __restrict__ F,   // [20,16]
    const float* __restrict__ M,   // [16,16]
    float* __restrict__ tab)       // [400] out (in d_ws)
{
    __shared__ float sF[NUM_AA * FEAT]; // 320 floats
    __shared__ float sM[FEAT * FEAT];   // 256 floats
    const int t = threadIdx.x;
    for (int k = t; k < NUM_AA * FEAT; k += 512) sF[k] = F[k];
    for (int k = t; k < FEAT * FEAT; k += 512)   sM[k] = M[k];
    __syncthreads();

    if (t < TABLE) {
        const int i = t / NUM_AA;
        const int j = t - i * NUM_AA;
        float delta[FEAT];
#pragma unroll
        for (int d = 0; d < FEAT; ++d)
            delta[d] = sF[i * FEAT + d] - sF[j * FEAT + d];
        float dist = 0.f;
#pragma unroll
        for (int d = 0; d < FEAT; ++d) {
            float md = 0.f;
#pragma unroll
            for (int e = 0; e < FEAT; ++e)
                md = fmaf(sM[d * FEAT + e], delta[e], md);
            dist = fmaf(delta[d], md, dist);
        }
        tab[t] = tanhf(dist);
    }
}

// ---------------- Kernel B: vectorized gather through LDS table -------------
__global__ __launch_bounds__(256) void gather_pairs(
    const float* __restrict__ tab,      // [400] in d_ws
    const int4* __restrict__ ii4,       // idx_i as int4
    const int4* __restrict__ jj4,       // idx_j as int4
    float4* __restrict__ out4,          // output as float4
    int nvec,                           // P/4
    const int* __restrict__ ii_s,       // scalar views for tail
    const int* __restrict__ jj_s,
    float* __restrict__ out_s,
    int tail_start, int total)          // tail handling (P % 4)
{
    __shared__ float s[TABLE]; // 1.6 KB
    for (int k = threadIdx.x; k < TABLE; k += 256) s[k] = tab[k];
    __syncthreads();

    const int v = blockIdx.x * 256 + threadIdx.x;
    if (v < nvec) {
        const int4 ii = ii4[v];
        const int4 jj = jj4[v];
        float4 o;
        o.x = s[ii.x * NUM_AA + jj.x];
        o.y = s[ii.y * NUM_AA + jj.y];
        o.z = s[ii.z * NUM_AA + jj.z];
        o.w = s[ii.w * NUM_AA + jj.w];
        out4[v] = o;
    }
    // tail (P % 4 != 0) — block 0 handles up to 3 scalars
    if (blockIdx.x == 0) {
        const int p = tail_start + (int)threadIdx.x;
        if (p < total)
            out_s[p] = s[ii_s[p] * NUM_AA + jj_s[p]];
    }
}

extern "C" void kernel_launch(void* const* d_in, const int* in_sizes, int n_in,
                              void* d_out, int out_size, void* d_ws, size_t ws_size,
                              hipStream_t stream)
{
    const float* F   = (const float*)d_in[0];
    const float* M   = (const float*)d_in[1];
    const int*   ii  = (const int*)d_in[2];
    const int*   jj  = (const int*)d_in[3];
    float*       out = (float*)d_out;
    float*       tab = (float*)d_ws;   // 400 floats = 1.6 KB scratch

    const int P    = in_sizes[2];
    const int nvec = P >> 2;           // 2,097,152 for P = 8,388,608
    const int tail = nvec << 2;        // first scalar index of tail (== P here)

    build_table<<<1, 512, 0, stream>>>(F, M, tab);

    const int blocks = (nvec + 255) / 256; // 8192
    gather_pairs<<<blocks, 256, 0, stream>>>(
        tab, (const int4*)ii, (const int4*)jj, (float4*)out,
        nvec, ii, jj, out, tail, P);
}